// Round 6
// baseline (236.320 us; speedup 1.0000x reference)
//
#include <hip/hip_runtime.h>
#include <math.h>

#define N_ 32
#define D_ 512
#define S_ 1600
#define K_ 64

typedef __attribute__((ext_vector_type(8))) short short8;   // 8 bf16 (A/B frag)
typedef __attribute__((ext_vector_type(4))) float f32x4;    // acc frag

// float -> bf16 (round to nearest even), bit pattern in short
static __device__ __forceinline__ short f2bf(float f) {
    unsigned u = __float_as_uint(f);
    u += 0x7fffu + ((u >> 16) & 1u);
    return (short)(u >> 16);
}

// ---------------------------------------------------------------------------
// kW: conv_weight [64][512] fp32 -> bf16
// ---------------------------------------------------------------------------
__global__ __launch_bounds__(256) void kW(const float* __restrict__ w,
                                          short* __restrict__ w16)
{
    int i4 = (blockIdx.x * 256 + threadIdx.x) * 4;   // 32 blocks: 32768 elems
    float4 v = *(const float4*)&w[i4];
    short4 h = {f2bf(v.x), f2bf(v.y), f2bf(v.z), f2bf(v.w)};
    *(short4*)&w16[i4] = h;
}

// ---------------------------------------------------------------------------
// kA: logits -> softmax -> aprime (= p*inv, bf16) + asum.
// 256 thr / 4 waves per block; block owns 16 s-columns; wave wv covers
// d in [128wv, 128wv+128) (4 fully-unrolled K-steps, 32 loads in flight).
// Grid 3200 blocks -> 12800 waves (12.5/SIMD grid-side; ~4-5 resident by
// VGPR) -- 4x the TLP of the r5 single-wave version, which was latency-
// bound at 22% HBM.
// Partial logits (16/lane) + partial ssq relay via pacc[4][64][17] LDS
// (pitch 17: gcd(17,32)=1 -> conflict-free); ONE barrier; every wave sums
// all 4 partials (redundant, cheap) and computes softmax; wave wv writes
// only k in [16wv, 16wv+16).
// B-frags gathered from global x (lane (q,lk): s = s0w+lk fixed,
// d = 128wv + 32kst + 8q + j). Every x element fetched exactly once.
// No-max softmax (|logits| <= ~||w_k|| ~ 1.2; verified r2-r5).
// MFMA conv: D[row=4q+r][col=lane&15]; row<-1st operand (k), col<-2nd (s).
// ---------------------------------------------------------------------------
__global__ __launch_bounds__(256) void kA(const float* __restrict__ x,
                                          const short* __restrict__ w16,
                                          short* __restrict__ aprime,
                                          float* __restrict__ asum)
{
    __shared__ float pacc[4][64][17];   // [wave][lane][16 logits + ssq] 17.4 KB

    const int tid = threadIdx.x;
    const int wv  = tid >> 6;           // d-range owner
    const int l   = tid & 63;
    const int lk  = l & 15;
    const int q   = l >> 4;
    const int n   = blockIdx.x / 100;
    const int s0w = (blockIdx.x % 100) * 16;

    const float* xcol = x + (size_t)n * D_ * S_ + s0w + lk;  // lane's s-column

    f32x4 accl[4];
#pragma unroll
    for (int kt = 0; kt < 4; ++kt) accl[kt] = (f32x4){0.f, 0.f, 0.f, 0.f};
    float ssq = 0.f;

#pragma unroll
    for (int kst = 0; kst < 4; ++kst) {
        const int d0 = wv * 128 + kst * 32 + q * 8;
        // B-frag: 8 strided gathers along d for this lane's s
        float xv[8];
#pragma unroll
        for (int j = 0; j < 8; ++j)
            xv[j] = xcol[(size_t)(d0 + j) * S_];
        short8 bf;
#pragma unroll
        for (int j = 0; j < 8; ++j) {
            ssq += xv[j] * xv[j];
            bf[j] = f2bf(xv[j]);
        }
        // A-frags from w16 (L2-resident, 64 KB) + MFMA
#pragma unroll
        for (int kt = 0; kt < 4; ++kt) {
            short8 af = *(const short8*)&w16[(size_t)(kt * 16 + lk) * D_ + d0];
            accl[kt] = __builtin_amdgcn_mfma_f32_16x16x32_bf16(af, bf, accl[kt], 0, 0, 0);
        }
    }

    // ---- relay partials through LDS (one barrier) ----
#pragma unroll
    for (int kt = 0; kt < 4; ++kt)
#pragma unroll
        for (int r = 0; r < 4; ++r)
            pacc[wv][l][kt * 4 + r] = accl[kt][r];
    pacc[wv][l][16] = ssq;
    __syncthreads();

    float tot[16];
#pragma unroll
    for (int i = 0; i < 16; ++i) tot[i] = pacc[0][l][i];
    float tssq = pacc[0][l][16];
#pragma unroll
    for (int w2 = 1; w2 < 4; ++w2) {
#pragma unroll
        for (int i = 0; i < 16; ++i) tot[i] += pacc[w2][l][i];
        tssq += pacc[w2][l][16];
    }

    // full ssq for this lane's s: sum over the 4 q-groups
    tssq += __shfl_xor(tssq, 16);
    tssq += __shfl_xor(tssq, 32);
    const float inv = 1.0f / fmaxf(sqrtf(tssq), 1e-12f);

    // softmax over all 64 k (16 in-lane + cross-q), no max subtraction
    float e[16];
    float sm = 0.f;
#pragma unroll
    for (int i = 0; i < 16; ++i) {
        e[i] = __expf(tot[i] * inv);
        sm += e[i];
    }
    sm += __shfl_xor(sm, 16);
    sm += __shfl_xor(sm, 32);
    const float rs = 1.0f / sm;

    // wave wv writes its k-quarter: k = 16wv + 4q + r
    short* apb = aprime + (size_t)n * K_ * S_ + s0w + lk;
#pragma unroll
    for (int r = 0; r < 4; ++r) {
        const float p = e[wv * 4 + r] * rs;
        apb[(size_t)(16 * wv + 4 * q + r) * S_] = f2bf(p * inv);
        float v = p;
        v += __shfl_xor(v, 1);
        v += __shfl_xor(v, 2);
        v += __shfl_xor(v, 4);
        v += __shfl_xor(v, 8);
        if (lk == 0) atomicAdd(&asum[n * K_ + 16 * wv + 4 * q + r], v);
    }
}

// ---------------------------------------------------------------------------
// kB: LDS-free MFMA GEMM (r0/r4 structure, verified). agg[k][d] over s-split:
//   agg[k][d] = sum_s aprime[k][s] * x[d][s]   (both s-contiguous row-major)
// grid: n(32) x dtile(4 of 128) x split(5 of 320s) = 640 blocks x 256 thr.
// Wave wv: d in [dt*128 + wv*32, +32), all 64 k, 10 K-steps of 32 s.
// Epilogue: atomicAdd into single agg buffer.
// ---------------------------------------------------------------------------
__global__ __launch_bounds__(256) void kB(const float* __restrict__ x,
                                          const short* __restrict__ aprime,
                                          float* __restrict__ agg)
{
    const int bid = blockIdx.x;
    const int n  = bid / 20;
    const int dt = (bid % 20) / 5;
    const int sp = bid % 5;
    const int wv = threadIdx.x >> 6;
    const int l  = threadIdx.x & 63;
    const int lk = l & 15;
    const int q  = l >> 4;
    const int dbase = dt * 128 + wv * 32;

    const short* ap = aprime + (size_t)n * K_ * S_;
    const float* xb = x + (size_t)n * D_ * S_;

    f32x4 acc[4][2];   // [ktile][dsub]
#pragma unroll
    for (int kt = 0; kt < 4; ++kt)
#pragma unroll
        for (int ds = 0; ds < 2; ++ds) acc[kt][ds] = (f32x4){0.f, 0.f, 0.f, 0.f};

    for (int kst = 0; kst < 10; ++kst) {
        const int s = sp * 320 + kst * 32 + q * 8;
        short8 af[4];
#pragma unroll
        for (int kt = 0; kt < 4; ++kt)
            af[kt] = *(const short8*)&ap[(size_t)(kt * 16 + lk) * S_ + s];
        short8 bf[2];
#pragma unroll
        for (int ds = 0; ds < 2; ++ds) {
            const float* xp = &xb[(size_t)(dbase + ds * 16 + lk) * S_ + s];
            float4 v0 = *(const float4*)xp;
            float4 v1 = *(const float4*)(xp + 4);
            short8 b;
            b[0] = f2bf(v0.x); b[1] = f2bf(v0.y); b[2] = f2bf(v0.z); b[3] = f2bf(v0.w);
            b[4] = f2bf(v1.x); b[5] = f2bf(v1.y); b[6] = f2bf(v1.z); b[7] = f2bf(v1.w);
            bf[ds] = b;
        }
#pragma unroll
        for (int kt = 0; kt < 4; ++kt)
#pragma unroll
            for (int ds = 0; ds < 2; ++ds)
                acc[kt][ds] = __builtin_amdgcn_mfma_f32_16x16x32_bf16(af[kt], bf[ds], acc[kt][ds], 0, 0, 0);
    }

    // atomic accumulate: agg[n][k][d]; D row=4q+r (k, 1st op), col=lk (d, 2nd)
    float* ab = agg + (size_t)n * K_ * D_;
#pragma unroll
    for (int kt = 0; kt < 4; ++kt)
#pragma unroll
        for (int ds = 0; ds < 2; ++ds)
#pragma unroll
            for (int r = 0; r < 4; ++r)
                atomicAdd(&ab[(size_t)(kt * 16 + 4 * q + r) * D_ + dbase + ds * 16 + lk],
                          acc[kt][ds][r]);
}

// ---------------------------------------------------------------------------
// kC: vlad = agg - asum*centroid; intra-L2-norm over d; global norm =
// /sqrt(K) = /8 exactly. grid: 2048 blocks x 256 thr (~8.5 MB total traffic).
// ---------------------------------------------------------------------------
__global__ __launch_bounds__(256) void kC(const float* __restrict__ agg,
                                          const float* __restrict__ asum,
                                          const float* __restrict__ cent,
                                          float* __restrict__ out)
{
    __shared__ float red[4];
    const int tid = threadIdx.x;
    const int nk = blockIdx.x;
    const int k = nk & 63;
    const float as = asum[nk];
    const float* cb = cent + (size_t)k * D_;
    const float* ag = agg + (size_t)nk * D_;

    float v0 = ag[tid]       - as * cb[tid];
    float v1 = ag[tid + 256] - as * cb[tid + 256];
    float ssq = v0 * v0 + v1 * v1;

    ssq += __shfl_xor(ssq, 32);
    ssq += __shfl_xor(ssq, 16);
    ssq += __shfl_xor(ssq, 8);
    ssq += __shfl_xor(ssq, 4);
    ssq += __shfl_xor(ssq, 2);
    ssq += __shfl_xor(ssq, 1);
    if ((tid & 63) == 0) red[tid >> 6] = ssq;
    __syncthreads();
    const float total = red[0] + red[1] + red[2] + red[3];
    const float scale = 1.0f / (fmaxf(sqrtf(total), 1e-12f) * 8.0f);

    out[(size_t)nk * D_ + tid]       = v0 * scale;
    out[(size_t)nk * D_ + tid + 256] = v1 * scale;
}

// ---------------------------------------------------------------------------
extern "C" void kernel_launch(void* const* d_in, const int* in_sizes, int n_in,
                              void* d_out, int out_size, void* d_ws, size_t ws_size,
                              hipStream_t stream)
{
    const float* x    = (const float*)d_in[0];   // [32,512,40,40]
    const float* w    = (const float*)d_in[1];   // [64,512]
    const float* cent = (const float*)d_in[2];   // [64,512]
    float* out = (float*)d_out;                  // [32, 32768]

    // ws carve (~10.8 MB), 16B-aligned throughout
    float* agg    = (float*)d_ws;                        // N*K*D fp32 (4.19 MB)
    float* asum   = agg + (size_t)N_ * K_ * D_;          // 2048 fp32
    short* aprime = (short*)(asum + N_ * K_);            // N*K*S bf16 (6.55 MB)
    short* w16    = aprime + (size_t)N_ * K_ * S_;       // 32768 bf16

    // zero agg + asum in one shot (adjacent)
    hipMemsetAsync(agg, 0, ((size_t)N_ * K_ * D_ + N_ * K_) * sizeof(float), stream);

    kW<<<32, 256, 0, stream>>>(w, w16);
    kA<<<N_ * (S_ / 16), 256, 0, stream>>>(x, w16, aprime, asum);
    kB<<<N_ * 4 * 5, 256, 0, stream>>>(x, aprime, agg);
    kC<<<N_ * K_, 256, 0, stream>>>(agg, asum, cent, out);
}

// Round 7
// 219.891 us; speedup vs baseline: 1.0747x; 1.0747x over previous
//
#include <hip/hip_runtime.h>
#include <math.h>

#define N_ 32
#define D_ 512
#define S_ 1600
#define K_ 64

typedef __attribute__((ext_vector_type(8))) short short8;   // 8 bf16 (A/B frag)
typedef __attribute__((ext_vector_type(4))) short short4v;  // 4 bf16 (8-B LDS ld)
typedef __attribute__((ext_vector_type(4))) float f32x4;    // acc frag
typedef __attribute__((ext_vector_type(2))) unsigned u32x2; // 8-B LDS store

// float -> bf16 (round to nearest even), bit pattern in short
static __device__ __forceinline__ short f2bf(float f) {
    unsigned u = __float_as_uint(f);
    u += 0x7fffu + ((u >> 16) & 1u);
    return (short)(u >> 16);
}
// pack two floats into (bf16(a) | bf16(b)<<16)
static __device__ __forceinline__ unsigned pk2(float a, float b) {
    return (unsigned)(unsigned short)f2bf(a) | ((unsigned)(unsigned short)f2bf(b) << 16);
}

// ---------------------------------------------------------------------------
// kW: conv_weight [64][512] fp32 -> bf16
// ---------------------------------------------------------------------------
__global__ __launch_bounds__(256) void kW(const float* __restrict__ w,
                                          short* __restrict__ w16)
{
    int i4 = (blockIdx.x * 256 + threadIdx.x) * 4;   // 32 blocks: 32768 elems
    float4 v = *(const float4*)&w[i4];
    short4 h = {f2bf(v.x), f2bf(v.y), f2bf(v.z), f2bf(v.w)};
    *(short4*)&w16[i4] = h;
}

// ---------------------------------------------------------------------------
// kA: logits -> softmax -> aprime (= p*inv, bf16) + asum.
// One block per (n, 64-s chunk): 800 blocks x 256 thr (4 waves).
// d processed in 8 chunks of 64, double-buffered T[2][64s][64d] (16 KB LDS):
// stage(c+1) issued BEFORE mfma(c) -> loads hide under compute; 1 barrier
// per chunk (10 total). Staging: fully-coalesced float4 rows (256 B / 16
// lanes), R4-verified 4x4 in-register shfl transpose, b64 stores.
// Bank swizzle: 8-B granule col4' = col4 ^ (row&15) -> stores AND 2xb64
// frag reads both hit the exact 32-bank floor (hand-traced).
// ssq from staging loads (lane's s-quad fixed); softmax = R4 epilogue.
// No-max softmax (|logits| <= ~1.2; verified r2-r6).
// MFMA conv: D[row=4q+r][col=lane&15]; row<-1st operand (k), col<-2nd (s).
// ---------------------------------------------------------------------------
__global__ __launch_bounds__(256) void kA(const float* __restrict__ x,
                                          const short* __restrict__ w16,
                                          short* __restrict__ aprime,
                                          float* __restrict__ asum)
{
    __shared__ short T[2][64 * 64];     // [buf][row(s)*64 + swizzled d] 16 KB
    __shared__ float invSS[64];         // atomic ssq accumulator
    __shared__ float wredS[4][66];      // cross-wave softmax sums

    const int tid = threadIdx.x;
    const int wv  = tid >> 6;
    const int l   = tid & 63;
    const int lk  = l & 15;
    const int q   = l >> 4;
    const int n   = blockIdx.x / 25;
    const int s0  = (blockIdx.x % 25) * 64;

    const float* xb = x + (size_t)n * D_ * S_;
    // load row base: thread loads x[d = 64c+16jj+4wv+q][s0+4lk..+3]
    const float* xrow = xb + (size_t)(4 * wv + q) * S_ + s0 + 4 * lk;
    // transposed store: row (s_t) = 4lk+q, col4 = 4jj+wv, swz col4^(row&15)
    const int row   = 4 * lk + q;
    const int rswz  = row & 15;

    float ssql[4] = {0.f, 0.f, 0.f, 0.f};
    f32x4 accl[4];
#pragma unroll
    for (int st = 0; st < 4; ++st) accl[st] = (f32x4){0.f, 0.f, 0.f, 0.f};

    if (tid < 64) invSS[tid] = 0.f;

    // ---- staging macro body: chunk c -> buffer b ----
#define STAGE(c, b)                                                          \
    {                                                                        \
        float4 v[4];                                                         \
        _Pragma("unroll")                                                    \
        for (int jj = 0; jj < 4; ++jj)                                       \
            v[jj] = *(const float4*)&xrow[(size_t)(64 * (c) + 16 * jj) * S_];\
        _Pragma("unroll")                                                    \
        for (int jj = 0; jj < 4; ++jj) {                                     \
            ssql[0] += v[jj].x * v[jj].x;  ssql[1] += v[jj].y * v[jj].y;     \
            ssql[2] += v[jj].z * v[jj].z;  ssql[3] += v[jj].w * v[jj].w;     \
            unsigned p0 = pk2(v[jj].x, v[jj].y), p1 = pk2(v[jj].z, v[jj].w); \
            unsigned mine = (l & 32) ? p0 : p1;                              \
            unsigned oth  = (unsigned)__shfl_xor((int)mine, 32);             \
            unsigned a0 = (l & 32) ? oth : p0;                               \
            unsigned a1 = (l & 32) ? p1 : oth;                               \
            unsigned r0 = (unsigned)__shfl_xor((int)a0, 16);                 \
            unsigned r1 = (unsigned)__shfl_xor((int)a1, 16);                 \
            unsigned o0, o1;                                                 \
            if (l & 16) {                                                    \
                o0 = (r0 >> 16) | (a0 & 0xffff0000u);                        \
                o1 = (r1 >> 16) | (a1 & 0xffff0000u);                        \
            } else {                                                         \
                o0 = (a0 & 0xffffu) | (r0 << 16);                            \
                o1 = (a1 & 0xffffu) | (r1 << 16);                            \
            }                                                                \
            *(u32x2*)&T[b][row * 64 + (((4 * jj + wv) ^ rswz) << 2)] =       \
                (u32x2){o0, o1};                                             \
        }                                                                    \
    }

    STAGE(0, 0);
    __syncthreads();   // T[0] ready, invSS zeroed

    for (int c = 0; c < 8; ++c) {
        if (c < 7) {
            if ((c & 1) == 0) STAGE(c + 1, 1) else STAGE(c + 1, 0)
        }
        // ---- logits MFMA on chunk c from T[c&1] ----
        const int b = c & 1;
#pragma unroll
        for (int kl = 0; kl < 2; ++kl) {
            short8 af = *(const short8*)&w16[(size_t)(16 * wv + lk) * D_
                                             + 64 * c + 32 * kl + 8 * q];
#pragma unroll
            for (int st = 0; st < 4; ++st) {
                const int rr = st * 16 + lk;
                const int c4 = 8 * kl + 2 * q;
                short4v pa = *(const short4v*)&T[b][rr * 64 + (((c4    ) ^ (rr & 15)) << 2)];
                short4v pb = *(const short4v*)&T[b][rr * 64 + (((c4 + 1) ^ (rr & 15)) << 2)];
                short8 bf = {pa[0], pa[1], pa[2], pa[3], pb[0], pb[1], pb[2], pb[3]};
                accl[st] = __builtin_amdgcn_mfma_f32_16x16x32_bf16(af, bf, accl[st], 0, 0, 0);
            }
        }
        if (c == 7) {
            // finalize ssq: reduce over q (shfl), then 1 atomic per (lk,i,wv)
#pragma unroll
            for (int i = 0; i < 4; ++i) {
                ssql[i] += __shfl_xor(ssql[i], 16);
                ssql[i] += __shfl_xor(ssql[i], 32);
            }
            if (q == 0) {
#pragma unroll
                for (int i = 0; i < 4; ++i) atomicAdd(&invSS[4 * lk + i], ssql[i]);
            }
        }
        __syncthreads();   // stores(c+1) visible; reads(c) done; c==7: invSS final
    }
#undef STAGE

    // ---- softmax over k (no max subtraction) ----
    float e[4][4], invv[4];
#pragma unroll
    for (int st = 0; st < 4; ++st) {
        invv[st] = 1.0f / fmaxf(sqrtf(invSS[st * 16 + lk]), 1e-12f);
        float sm = 0.f;
#pragma unroll
        for (int r = 0; r < 4; ++r) {
            e[st][r] = __expf(accl[st][r] * invv[st]);
            sm += e[st][r];
        }
        sm += __shfl_xor(sm, 16);
        sm += __shfl_xor(sm, 32);
        if (q == 0) wredS[wv][st * 16 + lk] = sm;
    }
    __syncthreads();

    float asum_loc[4] = {0.f, 0.f, 0.f, 0.f};
    short* apb = aprime + (size_t)n * K_ * S_ + s0;
#pragma unroll
    for (int st = 0; st < 4; ++st) {
        const int s = st * 16 + lk;
        const float rs = 1.0f / (wredS[0][s] + wredS[1][s]
                               + wredS[2][s] + wredS[3][s]);
#pragma unroll
        for (int r = 0; r < 4; ++r) {
            const float p = e[st][r] * rs;
            apb[(size_t)(16 * wv + 4 * q + r) * S_ + s] = f2bf(p * invv[st]);
            asum_loc[r] += p;
        }
    }
#pragma unroll
    for (int r = 0; r < 4; ++r) {
        float v = asum_loc[r];
        v += __shfl_xor(v, 1);  v += __shfl_xor(v, 2);
        v += __shfl_xor(v, 4);  v += __shfl_xor(v, 8);
        if (lk == 0) atomicAdd(&asum[n * K_ + 16 * wv + 4 * q + r], v);
    }
}

// ---------------------------------------------------------------------------
// kB: LDS-free MFMA GEMM (r0/r4 structure, verified). agg[k][d] over s-split:
//   agg[k][d] = sum_s aprime[k][s] * x[d][s]
// grid: n(32) x dtile(4 of 128) x split(10 of 160s) = 1280 blocks x 256 thr
// (20 waves/CU for its latency-bound small-segment loads; x L3-resident).
// Wave wv: d in [dt*128 + wv*32, +32), all 64 k, 5 K-steps of 32 s.
// Epilogue: atomicAdd into single agg buffer.
// ---------------------------------------------------------------------------
__global__ __launch_bounds__(256) void kB(const float* __restrict__ x,
                                          const short* __restrict__ aprime,
                                          float* __restrict__ agg)
{
    const int bid = blockIdx.x;
    const int n  = bid / 40;
    const int dt = (bid % 40) / 10;
    const int sp = bid % 10;
    const int wv = threadIdx.x >> 6;
    const int l  = threadIdx.x & 63;
    const int lk = l & 15;
    const int q  = l >> 4;
    const int dbase = dt * 128 + wv * 32;

    const short* ap = aprime + (size_t)n * K_ * S_;
    const float* xb = x + (size_t)n * D_ * S_;

    f32x4 acc[4][2];   // [ktile][dsub]
#pragma unroll
    for (int kt = 0; kt < 4; ++kt)
#pragma unroll
        for (int ds = 0; ds < 2; ++ds) acc[kt][ds] = (f32x4){0.f, 0.f, 0.f, 0.f};

#pragma unroll
    for (int kst = 0; kst < 5; ++kst) {
        const int s = sp * 160 + kst * 32 + q * 8;
        short8 af[4];
#pragma unroll
        for (int kt = 0; kt < 4; ++kt)
            af[kt] = *(const short8*)&ap[(size_t)(kt * 16 + lk) * S_ + s];
        short8 bf[2];
#pragma unroll
        for (int ds = 0; ds < 2; ++ds) {
            const float* xp = &xb[(size_t)(dbase + ds * 16 + lk) * S_ + s];
            float4 v0 = *(const float4*)xp;
            float4 v1 = *(const float4*)(xp + 4);
            short8 b;
            b[0] = f2bf(v0.x); b[1] = f2bf(v0.y); b[2] = f2bf(v0.z); b[3] = f2bf(v0.w);
            b[4] = f2bf(v1.x); b[5] = f2bf(v1.y); b[6] = f2bf(v1.z); b[7] = f2bf(v1.w);
            bf[ds] = b;
        }
#pragma unroll
        for (int kt = 0; kt < 4; ++kt)
#pragma unroll
            for (int ds = 0; ds < 2; ++ds)
                acc[kt][ds] = __builtin_amdgcn_mfma_f32_16x16x32_bf16(af[kt], bf[ds], acc[kt][ds], 0, 0, 0);
    }

    // atomic accumulate: agg[n][k][d]; D row=4q+r (k, 1st op), col=lk (d, 2nd)
    float* ab = agg + (size_t)n * K_ * D_;
#pragma unroll
    for (int kt = 0; kt < 4; ++kt)
#pragma unroll
        for (int ds = 0; ds < 2; ++ds)
#pragma unroll
            for (int r = 0; r < 4; ++r)
                atomicAdd(&ab[(size_t)(kt * 16 + 4 * q + r) * D_ + dbase + ds * 16 + lk],
                          acc[kt][ds][r]);
}

// ---------------------------------------------------------------------------
// kC: vlad = agg - asum*centroid; intra-L2-norm over d; global norm =
// /sqrt(K) = /8 exactly. grid: 2048 blocks x 256 thr (~8.5 MB total traffic).
// ---------------------------------------------------------------------------
__global__ __launch_bounds__(256) void kC(const float* __restrict__ agg,
                                          const float* __restrict__ asum,
                                          const float* __restrict__ cent,
                                          float* __restrict__ out)
{
    __shared__ float red[4];
    const int tid = threadIdx.x;
    const int nk = blockIdx.x;
    const int k = nk & 63;
    const float as = asum[nk];
    const float* cb = cent + (size_t)k * D_;
    const float* ag = agg + (size_t)nk * D_;

    float v0 = ag[tid]       - as * cb[tid];
    float v1 = ag[tid + 256] - as * cb[tid + 256];
    float ssq = v0 * v0 + v1 * v1;

    ssq += __shfl_xor(ssq, 32);
    ssq += __shfl_xor(ssq, 16);
    ssq += __shfl_xor(ssq, 8);
    ssq += __shfl_xor(ssq, 4);
    ssq += __shfl_xor(ssq, 2);
    ssq += __shfl_xor(ssq, 1);
    if ((tid & 63) == 0) red[tid >> 6] = ssq;
    __syncthreads();
    const float total = red[0] + red[1] + red[2] + red[3];
    const float scale = 1.0f / (fmaxf(sqrtf(total), 1e-12f) * 8.0f);

    out[(size_t)nk * D_ + tid]       = v0 * scale;
    out[(size_t)nk * D_ + tid + 256] = v1 * scale;
}

// ---------------------------------------------------------------------------
extern "C" void kernel_launch(void* const* d_in, const int* in_sizes, int n_in,
                              void* d_out, int out_size, void* d_ws, size_t ws_size,
                              hipStream_t stream)
{
    const float* x    = (const float*)d_in[0];   // [32,512,40,40]
    const float* w    = (const float*)d_in[1];   // [64,512]
    const float* cent = (const float*)d_in[2];   // [64,512]
    float* out = (float*)d_out;                  // [32, 32768]

    // ws carve (~10.8 MB), 16B-aligned throughout
    float* agg    = (float*)d_ws;                        // N*K*D fp32 (4.19 MB)
    float* asum   = agg + (size_t)N_ * K_ * D_;          // 2048 fp32
    short* aprime = (short*)(asum + N_ * K_);            // N*K*S bf16 (6.55 MB)
    short* w16    = aprime + (size_t)N_ * K_ * S_;       // 32768 bf16

    // zero agg + asum in one shot (adjacent)
    hipMemsetAsync(agg, 0, ((size_t)N_ * K_ * D_ + N_ * K_) * sizeof(float), stream);

    kW<<<32, 256, 0, stream>>>(w, w16);
    kA<<<N_ * (S_ / 64), 256, 0, stream>>>(x, w16, aprime, asum);
    kB<<<N_ * 4 * 10, 256, 0, stream>>>(x, aprime, agg);
    kC<<<N_ * K_, 256, 0, stream>>>(agg, asum, cent, out);
}

// Round 8
// 218.806 us; speedup vs baseline: 1.0800x; 1.0050x over previous
//
#include <hip/hip_runtime.h>
#include <math.h>

#define N_ 32
#define D_ 512
#define S_ 1600
#define K_ 64

typedef __attribute__((ext_vector_type(8))) short short8;   // 8 bf16 (A/B frag)
typedef __attribute__((ext_vector_type(4))) short short4v;  // 4 bf16 (8-B LDS ld)
typedef __attribute__((ext_vector_type(4))) float f32x4;    // acc frag
typedef __attribute__((ext_vector_type(2))) unsigned u32x2; // 8-B LDS store

// float -> bf16 (round to nearest even), bit pattern in short
static __device__ __forceinline__ short f2bf(float f) {
    unsigned u = __float_as_uint(f);
    u += 0x7fffu + ((u >> 16) & 1u);
    return (short)(u >> 16);
}
// pack two floats into (bf16(a) | bf16(b)<<16)
static __device__ __forceinline__ unsigned pk2(float a, float b) {
    return (unsigned)(unsigned short)f2bf(a) | ((unsigned)(unsigned short)f2bf(b) << 16);
}

// ---------------------------------------------------------------------------
// kW: conv_weight [64][512] fp32 -> bf16
// ---------------------------------------------------------------------------
__global__ __launch_bounds__(256) void kW(const float* __restrict__ w,
                                          short* __restrict__ w16)
{
    int i4 = (blockIdx.x * 256 + threadIdx.x) * 4;   // 32 blocks: 32768 elems
    float4 v = *(const float4*)&w[i4];
    short4 h = {f2bf(v.x), f2bf(v.y), f2bf(v.z), f2bf(v.w)};
    *(short4*)&w16[i4] = h;
}

// ---------------------------------------------------------------------------
// kA: logits -> softmax -> aprime (= p*inv, bf16) + asum.
// One block per (n, 32-s chunk): 1600 blocks x 256 thr (4 waves) ->
// 6.25 blocks/CU = 25 waves/CU (LDS ~9 KB, VGPR ~70; grid is the limiter).
// d in 8 chunks of 64, double-buffered T[2][32 s][64 d] (8 KB):
//   per chunk: issue loads(c+1) -> MFMA(c) -> transpose+store(c+1) -> barrier
// (T14 async split: HBM latency hides under MFMA+LDS instead of stalling
// the transpose). Staging: fully-coalesced float4 rows; R4/R7-verified 4x4
// in-register shfl transpose over lane groups {l, l^16, l^32, l^48}
// (group covers d = D0..D0+3, same s-quad; output lane q holds s=squad+q,
// d-run D0..D0+3). Bank swizzle col4 ^= row&15 -> stores and 2xb64 frag
// reads at the 32-bank floor. ssq piggybacked on staging; no-max softmax
// (|logits| <= ~1.2; verified r2-r7).
// Wave wv: k in [16wv,16wv+16) x all 32 s.
// MFMA conv: D[row=4q+r][col=lane&15]; row<-1st operand (k), col<-2nd (s).
// ---------------------------------------------------------------------------
__global__ __launch_bounds__(256) void kA(const float* __restrict__ x,
                                          const short* __restrict__ w16,
                                          short* __restrict__ aprime,
                                          float* __restrict__ asum)
{
    __shared__ short T[2][32 * 64];     // [buf][row(s)*64 + swizzled d] 8 KB
    __shared__ float invSS[32];         // atomic ssq accumulator
    __shared__ float wredS[4][34];      // cross-wave softmax sums

    const int tid = threadIdx.x;
    const int wv  = tid >> 6;
    const int l   = tid & 63;
    const int lk  = l & 15;
    const int q   = l >> 4;
    const int n   = blockIdx.x / 50;
    const int s0  = (blockIdx.x % 50) * 32;

    const float* xb = x + (size_t)n * D_ * S_;
    // thread loads x[d = 64c + 8(wv+4jj) + 4(lk>>3) + q][s0 + 4(lk&7) ..+3]
    const float* xrow = xb + (size_t)(4 * (lk >> 3) + q) * S_ + s0 + 4 * (lk & 7);
    // transposed store: row(s) = 4(lk&7)+q, col4 = 2(wv+4jj) + (lk>>3)
    const int row  = 4 * (lk & 7) + q;
    const int rsw  = row & 15;

    float ssql[4] = {0.f, 0.f, 0.f, 0.f};
    f32x4 accl[2];
    accl[0] = (f32x4){0.f, 0.f, 0.f, 0.f};
    accl[1] = accl[0];

    if (tid < 32) invSS[tid] = 0.f;

    float4 v0, v1;                       // in-flight staging registers
#define LOADC(c)                                                             \
    {                                                                        \
        v0 = *(const float4*)&xrow[(size_t)(64 * (c) + 8 * wv) * S_];        \
        v1 = *(const float4*)&xrow[(size_t)(64 * (c) + 8 * wv + 32) * S_];   \
    }
    // transpose one float4 (one d-row, 4 s) and store b64 into T[b]
#define TRN(v, b, c4)                                                        \
    {                                                                        \
        ssql[0] += v.x * v.x;  ssql[1] += v.y * v.y;                         \
        ssql[2] += v.z * v.z;  ssql[3] += v.w * v.w;                         \
        unsigned p0 = pk2(v.x, v.y), p1 = pk2(v.z, v.w);                     \
        unsigned mine = (l & 32) ? p0 : p1;                                  \
        unsigned oth  = (unsigned)__shfl_xor((int)mine, 32);                 \
        unsigned a0 = (l & 32) ? oth : p0;                                   \
        unsigned a1 = (l & 32) ? p1 : oth;                                   \
        unsigned r0 = (unsigned)__shfl_xor((int)a0, 16);                     \
        unsigned r1 = (unsigned)__shfl_xor((int)a1, 16);                     \
        unsigned o0, o1;                                                     \
        if (l & 16) {                                                        \
            o0 = (r0 >> 16) | (a0 & 0xffff0000u);                            \
            o1 = (r1 >> 16) | (a1 & 0xffff0000u);                            \
        } else {                                                             \
            o0 = (a0 & 0xffffu) | (r0 << 16);                                \
            o1 = (a1 & 0xffffu) | (r1 << 16);                                \
        }                                                                    \
        *(u32x2*)&T[b][row * 64 + ((((c4)) ^ rsw) << 2)] = (u32x2){o0, o1};  \
    }
#define STOREC(b)                                                            \
    {                                                                        \
        TRN(v0, b, 2 * wv + (lk >> 3));                                      \
        TRN(v1, b, 2 * (wv + 4) + (lk >> 3));                                \
    }

    // prologue: chunk 0
    LOADC(0);
    STOREC(0);
    __syncthreads();   // T[0] + invSS-zero ready

#pragma unroll
    for (int c = 0; c < 8; ++c) {
        if (c < 7) LOADC(c + 1);         // issue early (hide under MFMA)

        // ---- logits MFMA on chunk c from T[c&1] ----
        const int b = c & 1;
        const short* wbase = w16 + (size_t)(16 * wv + lk) * D_ + 64 * c + 8 * q;
#pragma unroll
        for (int kl = 0; kl < 2; ++kl) {
            short8 af = *(const short8*)&wbase[32 * kl];
#pragma unroll
            for (int st = 0; st < 2; ++st) {
                const int rr = st * 16 + lk;
                const int c4 = 8 * kl + 2 * q;
                short4v pa = *(const short4v*)&T[b][rr * 64 + (((c4    ) ^ lk) << 2)];
                short4v pb = *(const short4v*)&T[b][rr * 64 + (((c4 + 1) ^ lk) << 2)];
                short8 bf = {pa[0], pa[1], pa[2], pa[3], pb[0], pb[1], pb[2], pb[3]};
                accl[st] = __builtin_amdgcn_mfma_f32_16x16x32_bf16(af, bf, accl[st], 0, 0, 0);
            }
        }

        if (c < 7) {
            STOREC((c + 1) & 1);         // write late (loads have returned)
            __syncthreads();             // stores visible; reads(c) done
        }
    }
#undef LOADC
#undef TRN
#undef STOREC

    // ---- ssq: reduce over q (xor 16,32) and lk>>3 (xor 8), then atomics ----
#pragma unroll
    for (int i = 0; i < 4; ++i) {
        ssql[i] += __shfl_xor(ssql[i], 16);
        ssql[i] += __shfl_xor(ssql[i], 32);
        ssql[i] += __shfl_xor(ssql[i], 8);
    }
    if (l < 8) {
#pragma unroll
        for (int i = 0; i < 4; ++i) atomicAdd(&invSS[4 * l + i], ssql[i]);
    }
    __syncthreads();   // invSS final

    // ---- softmax over k (no max subtraction) ----
    float e[2][4], invv[2];
#pragma unroll
    for (int st = 0; st < 2; ++st) {
        invv[st] = 1.0f / fmaxf(sqrtf(invSS[st * 16 + lk]), 1e-12f);
        float sm = 0.f;
#pragma unroll
        for (int r = 0; r < 4; ++r) {
            e[st][r] = __expf(accl[st][r] * invv[st]);
            sm += e[st][r];
        }
        sm += __shfl_xor(sm, 16);
        sm += __shfl_xor(sm, 32);
        if (q == 0) wredS[wv][st * 16 + lk] = sm;
    }
    __syncthreads();

    float asum_loc[4] = {0.f, 0.f, 0.f, 0.f};
    short* apb = aprime + (size_t)n * K_ * S_ + s0;
#pragma unroll
    for (int st = 0; st < 2; ++st) {
        const int s = st * 16 + lk;
        const float rs = 1.0f / (wredS[0][s] + wredS[1][s]
                               + wredS[2][s] + wredS[3][s]);
#pragma unroll
        for (int r = 0; r < 4; ++r) {
            const float p = e[st][r] * rs;
            apb[(size_t)(16 * wv + 4 * q + r) * S_ + s] = f2bf(p * invv[st]);
            asum_loc[r] += p;
        }
    }
#pragma unroll
    for (int r = 0; r < 4; ++r) {
        float v = asum_loc[r];
        v += __shfl_xor(v, 1);  v += __shfl_xor(v, 2);
        v += __shfl_xor(v, 4);  v += __shfl_xor(v, 8);
        if (lk == 0) atomicAdd(&asum[n * K_ + 16 * wv + 4 * q + r], v);
    }
}

// ---------------------------------------------------------------------------
// kB: LDS-free MFMA GEMM (r0/r4 structure, verified). agg[k][d] over s-split:
//   agg[k][d] = sum_s aprime[k][s] * x[d][s]
// grid: n(32) x dtile(4 of 128) x split(10 of 160s) = 1280 blocks x 256 thr
// (20 waves/CU for its latency-bound small-segment loads; x L3-resident).
// Wave wv: d in [dt*128 + wv*32, +32), all 64 k, 5 K-steps of 32 s.
// Epilogue: atomicAdd into single agg buffer.
// ---------------------------------------------------------------------------
__global__ __launch_bounds__(256) void kB(const float* __restrict__ x,
                                          const short* __restrict__ aprime,
                                          float* __restrict__ agg)
{
    const int bid = blockIdx.x;
    const int n  = bid / 40;
    const int dt = (bid % 40) / 10;
    const int sp = bid % 10;
    const int wv = threadIdx.x >> 6;
    const int l  = threadIdx.x & 63;
    const int lk = l & 15;
    const int q  = l >> 4;
    const int dbase = dt * 128 + wv * 32;

    const short* ap = aprime + (size_t)n * K_ * S_;
    const float* xb = x + (size_t)n * D_ * S_;

    f32x4 acc[4][2];   // [ktile][dsub]
#pragma unroll
    for (int kt = 0; kt < 4; ++kt)
#pragma unroll
        for (int ds = 0; ds < 2; ++ds) acc[kt][ds] = (f32x4){0.f, 0.f, 0.f, 0.f};

#pragma unroll
    for (int kst = 0; kst < 5; ++kst) {
        const int s = sp * 160 + kst * 32 + q * 8;
        short8 af[4];
#pragma unroll
        for (int kt = 0; kt < 4; ++kt)
            af[kt] = *(const short8*)&ap[(size_t)(kt * 16 + lk) * S_ + s];
        short8 bf[2];
#pragma unroll
        for (int ds = 0; ds < 2; ++ds) {
            const float* xp = &xb[(size_t)(dbase + ds * 16 + lk) * S_ + s];
            float4 v0 = *(const float4*)xp;
            float4 v1 = *(const float4*)(xp + 4);
            short8 b;
            b[0] = f2bf(v0.x); b[1] = f2bf(v0.y); b[2] = f2bf(v0.z); b[3] = f2bf(v0.w);
            b[4] = f2bf(v1.x); b[5] = f2bf(v1.y); b[6] = f2bf(v1.z); b[7] = f2bf(v1.w);
            bf[ds] = b;
        }
#pragma unroll
        for (int kt = 0; kt < 4; ++kt)
#pragma unroll
            for (int ds = 0; ds < 2; ++ds)
                acc[kt][ds] = __builtin_amdgcn_mfma_f32_16x16x32_bf16(af[kt], bf[ds], acc[kt][ds], 0, 0, 0);
    }

    // atomic accumulate: agg[n][k][d]; D row=4q+r (k, 1st op), col=lk (d, 2nd)
    float* ab = agg + (size_t)n * K_ * D_;
#pragma unroll
    for (int kt = 0; kt < 4; ++kt)
#pragma unroll
        for (int ds = 0; ds < 2; ++ds)
#pragma unroll
            for (int r = 0; r < 4; ++r)
                atomicAdd(&ab[(size_t)(kt * 16 + 4 * q + r) * D_ + dbase + ds * 16 + lk],
                          acc[kt][ds][r]);
}

// ---------------------------------------------------------------------------
// kC: vlad = agg - asum*centroid; intra-L2-norm over d; global norm =
// /sqrt(K) = /8 exactly. grid: 2048 blocks x 256 thr (~8.5 MB total traffic).
// ---------------------------------------------------------------------------
__global__ __launch_bounds__(256) void kC(const float* __restrict__ agg,
                                          const float* __restrict__ asum,
                                          const float* __restrict__ cent,
                                          float* __restrict__ out)
{
    __shared__ float red[4];
    const int tid = threadIdx.x;
    const int nk = blockIdx.x;
    const int k = nk & 63;
    const float as = asum[nk];
    const float* cb = cent + (size_t)k * D_;
    const float* ag = agg + (size_t)nk * D_;

    float v0 = ag[tid]       - as * cb[tid];
    float v1 = ag[tid + 256] - as * cb[tid + 256];
    float ssq = v0 * v0 + v1 * v1;

    ssq += __shfl_xor(ssq, 32);
    ssq += __shfl_xor(ssq, 16);
    ssq += __shfl_xor(ssq, 8);
    ssq += __shfl_xor(ssq, 4);
    ssq += __shfl_xor(ssq, 2);
    ssq += __shfl_xor(ssq, 1);
    if ((tid & 63) == 0) red[tid >> 6] = ssq;
    __syncthreads();
    const float total = red[0] + red[1] + red[2] + red[3];
    const float scale = 1.0f / (fmaxf(sqrtf(total), 1e-12f) * 8.0f);

    out[(size_t)nk * D_ + tid]       = v0 * scale;
    out[(size_t)nk * D_ + tid + 256] = v1 * scale;
}

// ---------------------------------------------------------------------------
extern "C" void kernel_launch(void* const* d_in, const int* in_sizes, int n_in,
                              void* d_out, int out_size, void* d_ws, size_t ws_size,
                              hipStream_t stream)
{
    const float* x    = (const float*)d_in[0];   // [32,512,40,40]
    const float* w    = (const float*)d_in[1];   // [64,512]
    const float* cent = (const float*)d_in[2];   // [64,512]
    float* out = (float*)d_out;                  // [32, 32768]

    // ws carve (~10.8 MB), 16B-aligned throughout
    float* agg    = (float*)d_ws;                        // N*K*D fp32 (4.19 MB)
    float* asum   = agg + (size_t)N_ * K_ * D_;          // 2048 fp32
    short* aprime = (short*)(asum + N_ * K_);            // N*K*S bf16 (6.55 MB)
    short* w16    = aprime + (size_t)N_ * K_ * S_;       // 32768 bf16

    // zero agg + asum in one shot (adjacent)
    hipMemsetAsync(agg, 0, ((size_t)N_ * K_ * D_ + N_ * K_) * sizeof(float), stream);

    kW<<<32, 256, 0, stream>>>(w, w16);
    kA<<<N_ * (S_ / 32), 256, 0, stream>>>(x, w16, aprime, asum);
    kB<<<N_ * 4 * 10, 256, 0, stream>>>(x, aprime, agg);
    kC<<<N_ * K_, 256, 0, stream>>>(agg, asum, cent, out);
}